// Round 7
// baseline (440.006 us; speedup 1.0000x reference)
//
#include <hip/hip_runtime.h>

#define N_NODES 50000
#define DIM 256
#define NEG 0.2f
#define LN_EPS 1e-5f
#define SCAT_BLOCKS 2048
#define NT16 3125             // 50000/16 micro-tiles of 16 nodes (exact, no tail)
#define NWAVES 2048           // 256 blocks x 8 waves, persistent

typedef __attribute__((ext_vector_type(8))) short short8;   // 8 x bf16 (4 VGPRs)
typedef __attribute__((ext_vector_type(4))) float f32x4;    // MFMA accumulator

__device__ __forceinline__ unsigned short f2bf(float x) {   // RNE fp32 -> bf16
    unsigned int u = __builtin_bit_cast(unsigned int, x);
    u += 0x7fffu + ((u >> 16) & 1u);
    return (unsigned short)(u >> 16);
}

__device__ __forceinline__ void load_lds16(const void* g, void* l) {
    // async global->LDS, 16B/lane, dest = wave-uniform base + lane*16 (linear)
    __builtin_amdgcn_global_load_lds((const unsigned int*)g, (unsigned int*)l, 16, 0, 0);
}

__device__ __forceinline__ short8 cvt_bfrag(float4 a4, float4 b4) {
    short8 r;
    r[0] = (short)f2bf(a4.x); r[1] = (short)f2bf(a4.y);
    r[2] = (short)f2bf(a4.z); r[3] = (short)f2bf(a4.w);
    r[4] = (short)f2bf(b4.x); r[5] = (short)f2bf(b4.y);
    r[6] = (short)f2bf(b4.z); r[7] = (short)f2bf(b4.w);
    return r;
}

// ---------- prep: Wr -> fragment-ordered bf16 WrF  +  relation byte-mask scatter ----------
// WrF layout (proven r2-r6): frag f = kk*16+mt (kk = 32-wide k-step, mt = 16-col m-tile),
// 64 lanes x 16B: WrF[(f*64+lane)*8 + j] = bf16(Wr[kk*32 + (lane>>4)*8 + j][mt*16 + (lane&15)])
__global__ __launch_bounds__(256) void prep(
    const float* __restrict__ Wr, unsigned short* __restrict__ WrF,
    const int* __restrict__ d0, const int* __restrict__ d1, const int* __restrict__ d2,
    int E, unsigned char* __restrict__ mask)
{
    if (blockIdx.x < 32) {                       // 32*256 = 8192 = 128 frags x 64 lanes
        const int o    = blockIdx.x * 256 + threadIdx.x;
        const int lane = o & 63;
        const int frag = o >> 6;                 // kk*16 + mt
        const int mt = frag & 15, kk = frag >> 4;
        const int ln = lane & 15, quad = lane >> 4;
        const float* src = Wr + (size_t)(kk * 32 + quad * 8) * DIM + mt * 16 + ln;
        short8 v;
        #pragma unroll
        for (int j = 0; j < 8; ++j) v[j] = (short)f2bf(src[(size_t)j * DIM]);
        *(short8*)(WrF + (size_t)o * 8) = v;
    } else {
        // racing byte-stores of the same value are benign; memset zeroed the mask
        const int total = 3 * E;
        for (int i = (blockIdx.x - 32) * 256 + (int)threadIdx.x; i < total;
             i += SCAT_BLOCKS * 256) {
            const int* d; int base, e;
            if (i >= 2 * E)  { d = d2; e = i - 2 * E; base = 2 * N_NODES; }
            else if (i >= E) { d = d1; e = i - E;     base = N_NODES; }
            else             { d = d0; e = i;         base = 0; }
            mask[base + d[e]] = (unsigned char)1;
        }
    }
}

// ---------- persistent fused GEMM: W resident in LDS, barrier-free main loop ----------
// 256 blocks x 512 threads, 1 block/CU (128 KB LDS), 8 waves/CU. Stage full WrF
// once -> one __syncthreads -> each WAVE independently processes 16-node tiles
// (t = gwid; t < 3125; t += 2048). Per tile NOTHING is loop-carried but t:
// 16 feat loads -> bf16 convert in TWO 8-load chunks (peak F 32 + bfr 32 regs;
// r6's loop-carried FA/FB[8] prefetch caused 650 MB of scratch spill traffic) ->
// 128 conflict-free ds_read_b128 + 128 MFMA from resident W -> epilogue -> store.
// __launch_bounds__(512,1): no compiler register cap (LDS already limits
// occupancy to 8 waves/CU, so generous allocation is free).
__global__ __launch_bounds__(512, 1) void fused_mfma(
    const float* __restrict__ feat, const unsigned short* __restrict__ WrF,
    const float* __restrict__ br, const float* __restrict__ rel_q,
    const float* __restrict__ rel_k, const float* __restrict__ gamma,
    const float* __restrict__ beta_p, const unsigned char* __restrict__ mask,
    float* __restrict__ out)
{
    __shared__ unsigned short lds[65536];        // 128 KB: full WrF, resident
    const int lane = threadIdx.x & 63;
    const int wave = threadIdx.x >> 6;           // 0..7
    const int ln = lane & 15;      // node within wave / MFMA n
    const int quad = lane >> 4;    // MFMA k-quad & D-row-quad
    const int gwid = blockIdx.x * 8 + wave;      // 0..2047, global wave id

    // ---- stage full WrF once: 128 x 1KB chunks, 16 per wave ----
    {
        const char* g = (const char*)WrF;
        #pragma unroll
        for (int r = 0; r < 16; ++r) {
            const int off = (wave * 16 + r) * 1024;      // wave-uniform LDS base
            load_lds16(g + off + lane * 16, (char*)lds + off);
        }
    }
    __syncthreads();                             // W staged; only barrier in kernel

    for (int t = gwid; t < NT16; t += NWAVES) {
        const int node = t * 16 + ln;            // always < 50000 (3125*16 exact)

        // mask bytes (epilogue-only; issue first, latency hides under GEMM)
        const int m0 = (int)mask[node];
        const int m1 = (int)mask[N_NODES + node];
        const int m2 = (int)mask[2 * N_NODES + node];

        // feat row -> bf16 B-fragments, two 8-load chunks (low register peak)
        const float* fptr = feat + (size_t)node * DIM + quad * 8;
        short8 bfr[8];
        {
            float4 F[8];
            #pragma unroll
            for (int kk = 0; kk < 4; ++kk) {
                F[2 * kk]     = *(const float4*)(fptr + kk * 32);
                F[2 * kk + 1] = *(const float4*)(fptr + kk * 32 + 4);
            }
            #pragma unroll
            for (int kk = 0; kk < 4; ++kk) bfr[kk] = cvt_bfrag(F[2 * kk], F[2 * kk + 1]);
            #pragma unroll
            for (int kk = 0; kk < 4; ++kk) {
                F[2 * kk]     = *(const float4*)(fptr + (kk + 4) * 32);
                F[2 * kk + 1] = *(const float4*)(fptr + (kk + 4) * 32 + 4);
            }
            #pragma unroll
            for (int kk = 0; kk < 4; ++kk) bfr[4 + kk] = cvt_bfrag(F[2 * kk], F[2 * kk + 1]);
        }

        f32x4 acc[16];
        #pragma unroll
        for (int mt = 0; mt < 16; ++mt) acc[mt] = (f32x4){0.f, 0.f, 0.f, 0.f};

        #pragma unroll
        for (int kk = 0; kk < 8; ++kk) {
            #pragma unroll
            for (int mt = 0; mt < 16; ++mt) {
                const short8 a = *(const short8*)((const char*)lds
                                   + (kk * 16 + mt) * 1024 + lane * 16);
                acc[mt] = __builtin_amdgcn_mfma_f32_16x16x32_bf16(a, bfr[kk], acc[mt], 0, 0, 0);
            }
        }

        // ---- epilogue: bias, per-head dots, softmax weight, ReLU, LayerNorm ----
        float qp[4] = {0.f, 0.f, 0.f, 0.f}, kp[4] = {0.f, 0.f, 0.f, 0.f};
        #pragma unroll
        for (int mt = 0; mt < 16; ++mt) {
            const int cbase = mt * 16 + quad * 4;
            const float4 bb = *(const float4*)(br + cbase);
            acc[mt][0] += bb.x; acc[mt][1] += bb.y; acc[mt][2] += bb.z; acc[mt][3] += bb.w;
            const float4 rq = *(const float4*)(rel_q + cbase);
            const float4 rk = *(const float4*)(rel_k + cbase);
            const int h = mt >> 2;
            qp[h] += acc[mt][0] * rq.x + acc[mt][1] * rq.y + acc[mt][2] * rq.z + acc[mt][3] * rq.w;
            kp[h] += acc[mt][0] * rk.x + acc[mt][1] * rk.y + acc[mt][2] * rk.z + acc[mt][3] * rk.w;
        }
        #pragma unroll
        for (int h = 0; h < 4; ++h) {
            qp[h] += __shfl_xor(qp[h], 16); qp[h] += __shfl_xor(qp[h], 32);
            kp[h] += __shfl_xor(kp[h], 16); kp[h] += __shfl_xor(kp[h], 32);
        }

        const int cnt = m0 + m1 + m2;

        float wgt[4];
        #pragma unroll
        for (int h = 0; h < 4; ++h) {
            const float q = qp[h];
            const float qk = q + kp[h];
            const float a = q  > 0.f ? q  : NEG * q;    // inactive-relation logit
            const float b = qk > 0.f ? qk : NEG * qk;   // active/self logit
            const float mx = fmaxf(a, b);
            const float eb = (float)(cnt + 1) * __expf(b - mx);
            const float ea = (float)(3 - cnt) * __expf(a - mx);
            wgt[h] = eb / (eb + ea);
        }

        float sum = 0.f, ssq = 0.f;
        #pragma unroll
        for (int mt = 0; mt < 16; ++mt) {
            const float w = wgt[mt >> 2];
            #pragma unroll
            for (int r = 0; r < 4; ++r) {
                float v = fmaxf(acc[mt][r] * w, 0.f);   // ReLU
                acc[mt][r] = v;
                sum += v; ssq += v * v;
            }
        }
        sum += __shfl_xor(sum, 16); sum += __shfl_xor(sum, 32);
        ssq += __shfl_xor(ssq, 16); ssq += __shfl_xor(ssq, 32);
        const float mu = sum * (1.f / 256.f);
        const float var = ssq * (1.f / 256.f) - mu * mu;
        const float rstd = rsqrtf(var + LN_EPS);

        {
            float* optr = out + (size_t)node * DIM;
            #pragma unroll
            for (int mt = 0; mt < 16; ++mt) {
                const int cbase = mt * 16 + quad * 4;
                const float4 g = *(const float4*)(gamma + cbase);
                const float4 b = *(const float4*)(beta_p + cbase);
                float4 r;
                r.x = (acc[mt][0] - mu) * rstd * g.x + b.x;
                r.y = (acc[mt][1] - mu) * rstd * g.y + b.y;
                r.z = (acc[mt][2] - mu) * rstd * g.z + b.z;
                r.w = (acc[mt][3] - mu) * rstd * g.w + b.w;
                *(float4*)(optr + cbase) = r;
            }
        }
    }
}

extern "C" void kernel_launch(void* const* d_in, const int* in_sizes, int n_in,
                              void* d_out, int out_size, void* d_ws, size_t ws_size,
                              hipStream_t stream) {
    const float* feat  = (const float*)d_in[0];
    // d_in[1] Wl, d_in[2] bl, d_in[5] attn_l, d_in[6] attn_r, edge_src_*: dead code
    const float* Wr    = (const float*)d_in[3];
    const float* br    = (const float*)d_in[4];
    const float* rel_q = (const float*)d_in[7];
    const float* rel_k = (const float*)d_in[8];
    const float* gamma = (const float*)d_in[9];
    const float* beta  = (const float*)d_in[10];
    const int* dst0 = (const int*)d_in[12];
    const int* dst1 = (const int*)d_in[14];
    const int* dst2 = (const int*)d_in[16];
    const int E = in_sizes[12];

    // d_ws layout: WrF fragment-ordered bf16 (131072 B) | byte mask (150016 B)
    unsigned short* WrF = (unsigned short*)d_ws;
    unsigned char* mask = (unsigned char*)d_ws + DIM * DIM * 2;

    hipMemsetAsync(mask, 0, 150016, stream);
    prep<<<32 + SCAT_BLOCKS, 256, 0, stream>>>(Wr, WrF, dst0, dst1, dst2, E, mask);
    fused_mfma<<<256, 512, 0, stream>>>(
        feat, WrF, br, rel_q, rel_k, gamma, beta, mask, (float*)d_out);
}

// Round 8
// 159.403 us; speedup vs baseline: 2.7603x; 2.7603x over previous
//
#include <hip/hip_runtime.h>

#define N_NODES 50000
#define DIM 256
#define NEG 0.2f
#define LN_EPS 1e-5f
#define SCAT_BLOCKS 2048

typedef __attribute__((ext_vector_type(8))) short short8;   // 8 x bf16 (4 VGPRs)
typedef __attribute__((ext_vector_type(4))) float f32x4;    // MFMA accumulator

__device__ __forceinline__ unsigned short f2bf(float x) {   // RNE fp32 -> bf16
    unsigned int u = __builtin_bit_cast(unsigned int, x);
    u += 0x7fffu + ((u >> 16) & 1u);
    return (unsigned short)(u >> 16);
}

__device__ __forceinline__ void load_lds16(const void* g, void* l) {
    // async global->LDS, 16B/lane, dest = wave-uniform base + lane*16 (linear)
    __builtin_amdgcn_global_load_lds((const unsigned int*)g, (unsigned int*)l, 16, 0, 0);
}

__device__ __forceinline__ short8 cvt_bfrag(float4 a4, float4 b4) {
    short8 r;
    r[0] = (short)f2bf(a4.x); r[1] = (short)f2bf(a4.y);
    r[2] = (short)f2bf(a4.z); r[3] = (short)f2bf(a4.w);
    r[4] = (short)f2bf(b4.x); r[5] = (short)f2bf(b4.y);
    r[6] = (short)f2bf(b4.z); r[7] = (short)f2bf(b4.w);
    return r;
}

// ---------- prep: Wr -> fragment-ordered bf16 WrF  +  relation byte-mask scatter ----------
// WrF layout (proven r2-r7): frag f = kk*16+mt (kk = 32-wide k-step, mt = 16-col m-tile),
// 64 lanes x 16B: WrF[(f*64+lane)*8 + j] = bf16(Wr[kk*32 + (lane>>4)*8 + j][mt*16 + (lane&15)])
__global__ __launch_bounds__(256) void prep(
    const float* __restrict__ Wr, unsigned short* __restrict__ WrF,
    const int* __restrict__ d0, const int* __restrict__ d1, const int* __restrict__ d2,
    int E, unsigned char* __restrict__ mask)
{
    if (blockIdx.x < 32) {                       // 32*256 = 8192 = 128 frags x 64 lanes
        const int o    = blockIdx.x * 256 + threadIdx.x;
        const int lane = o & 63;
        const int frag = o >> 6;                 // kk*16 + mt
        const int mt = frag & 15, kk = frag >> 4;
        const int ln = lane & 15, quad = lane >> 4;
        const float* src = Wr + (size_t)(kk * 32 + quad * 8) * DIM + mt * 16 + ln;
        short8 v;
        #pragma unroll
        for (int j = 0; j < 8; ++j) v[j] = (short)f2bf(src[(size_t)j * DIM]);
        *(short8*)(WrF + (size_t)o * 8) = v;
    } else {
        // racing byte-stores of the same value are benign; memset zeroed the mask
        const int total = 3 * E;
        for (int i = (blockIdx.x - 32) * 256 + (int)threadIdx.x; i < total;
             i += SCAT_BLOCKS * 256) {
            const int* d; int base, e;
            if (i >= 2 * E)  { d = d2; e = i - 2 * E; base = 2 * N_NODES; }
            else if (i >= E) { d = d1; e = i - E;     base = N_NODES; }
            else             { d = d0; e = i;         base = 0; }
            mask[base + d[e]] = (unsigned char)1;
        }
    }
}

// ---------- fused MFMA GEMM + analytic-collapse epilogue (r1 structure, 80 KB LDS) ----------
// Block = 4 waves x 16 nodes = 64 nodes, all 256 out-cols, K=256. 2 blocks/CU
// (2 x 80 KB = full 160 KB LDS). Schedule per block:
//   stage ksteps 0-4 (80 KB) + feat prefetch + bfr convert -> sync (vmcnt drain)
//   -> MFMA ksteps 0-3 (from region A) -> sync (readers of A done)
//   -> issue restage ksteps 5-7 (48 KB into A) || MFMA kstep 4 (from region B,
//      already resident: overlaps restage latency) -> sync (drain: A ready)
//   -> MFMA ksteps 5-7 -> epilogue.
// vs r1: second stage shrinks 64->48 KB and 16 MFMAs hide under it. All math,
// layouts, and accumulation order (kk ascending per acc[mt]) verbatim r1 ->
// bit-identical output. Registers: ~112 arch + 64 acc (r1-proven, no spill).
__global__ __launch_bounds__(256, 2) void fused_mfma(
    const float* __restrict__ feat, const unsigned short* __restrict__ WrF,
    const float* __restrict__ br, const float* __restrict__ rel_q,
    const float* __restrict__ rel_k, const float* __restrict__ gamma,
    const float* __restrict__ beta_p, const unsigned char* __restrict__ mask,
    float* __restrict__ out)
{
    __shared__ unsigned short lds[40960];        // 80 KB: A = [0,64K) ping, B = [64K,80K) kstep4
    const int lane = threadIdx.x & 63;
    const int wave = threadIdx.x >> 6;
    const int ln = lane & 15;      // node within wave / MFMA n
    const int quad = lane >> 4;    // MFMA k-quad & D-row-quad
    int node = blockIdx.x * 64 + wave * 16 + ln;
    const bool valid = node < N_NODES;
    if (!valid) node = N_NODES - 1;              // clamp: loads safe, store guarded

    // ---- stage ksteps 0-3 into A (16 x 1KB per wave) + kstep 4 into B (4 x 1KB) ----
    {
        const char* g = (const char*)WrF;
        #pragma unroll
        for (int r = 0; r < 16; ++r) {
            const int off = wave * 16384 + r * 1024;     // wave-uniform LDS base
            load_lds16(g + off + lane * 16, (char*)lds + off);
        }
        #pragma unroll
        for (int r = 0; r < 4; ++r) {
            const int off = wave * 4096 + r * 1024;      // within kstep-4 block
            load_lds16(g + 65536 + off + lane * 16, (char*)lds + 65536 + off);
        }
    }

    // mask bytes (epilogue-only; hide latency now)
    const int m0 = (int)mask[node];
    const int m1 = (int)mask[N_NODES + node];
    const int m2 = (int)mask[2 * N_NODES + node];

    // full feat-row prefetch + one-time bf16 conversion (r1-proven)
    const float* fptr = feat + (size_t)node * DIM + quad * 8;
    float4 F0[8], F1[8];
    #pragma unroll
    for (int kk = 0; kk < 8; ++kk) {
        F0[kk] = *(const float4*)(fptr + kk * 32);
        F1[kk] = *(const float4*)(fptr + kk * 32 + 4);
    }
    short8 bfr[8];
    #pragma unroll
    for (int kk = 0; kk < 8; ++kk) bfr[kk] = cvt_bfrag(F0[kk], F1[kk]);

    f32x4 acc[16];
    #pragma unroll
    for (int mt = 0; mt < 16; ++mt) acc[mt] = (f32x4){0.f, 0.f, 0.f, 0.f};

    __syncthreads();                             // vmcnt drain: ksteps 0-4 staged

    #pragma unroll
    for (int kk = 0; kk < 4; ++kk) {
        #pragma unroll
        for (int mt = 0; mt < 16; ++mt) {
            const short8 a = *(const short8*)((const char*)lds
                               + (kk * 16 + mt) * 1024 + lane * 16);
            acc[mt] = __builtin_amdgcn_mfma_f32_16x16x32_bf16(a, bfr[kk], acc[mt], 0, 0, 0);
        }
    }

    __syncthreads();                             // all waves done reading A (ksteps 0-3)

    // issue restage of ksteps 5-7 into A (48 chunks: 12 x 1KB per wave) ...
    {
        const char* g = (const char*)WrF + 81920;        // kstep-5 source base
        #pragma unroll
        for (int r = 0; r < 12; ++r) {
            const int off = (wave * 12 + r) * 1024;
            load_lds16(g + off + lane * 16, (char*)lds + off);
        }
    }
    // ... and compute kstep 4 from resident B while those loads are in flight
    #pragma unroll
    for (int mt = 0; mt < 16; ++mt) {
        const short8 a = *(const short8*)((const char*)lds
                           + 65536 + mt * 1024 + lane * 16);
        acc[mt] = __builtin_amdgcn_mfma_f32_16x16x32_bf16(a, bfr[4], acc[mt], 0, 0, 0);
    }

    __syncthreads();                             // vmcnt drain: ksteps 5-7 staged

    #pragma unroll
    for (int kk = 5; kk < 8; ++kk) {
        #pragma unroll
        for (int mt = 0; mt < 16; ++mt) {
            const short8 a = *(const short8*)((const char*)lds
                               + ((kk - 5) * 16 + mt) * 1024 + lane * 16);
            acc[mt] = __builtin_amdgcn_mfma_f32_16x16x32_bf16(a, bfr[kk], acc[mt], 0, 0, 0);
        }
    }

    // ---- epilogue: bias, per-head dots, softmax weight, ReLU, LayerNorm (verbatim r1) ----
    float qp[4] = {0.f, 0.f, 0.f, 0.f}, kp[4] = {0.f, 0.f, 0.f, 0.f};
    #pragma unroll
    for (int mt = 0; mt < 16; ++mt) {
        const int cbase = mt * 16 + quad * 4;
        const float4 bb = *(const float4*)(br + cbase);
        acc[mt][0] += bb.x; acc[mt][1] += bb.y; acc[mt][2] += bb.z; acc[mt][3] += bb.w;
        const float4 rq = *(const float4*)(rel_q + cbase);
        const float4 rk = *(const float4*)(rel_k + cbase);
        const int h = mt >> 2;
        qp[h] += acc[mt][0] * rq.x + acc[mt][1] * rq.y + acc[mt][2] * rq.z + acc[mt][3] * rq.w;
        kp[h] += acc[mt][0] * rk.x + acc[mt][1] * rk.y + acc[mt][2] * rk.z + acc[mt][3] * rk.w;
    }
    #pragma unroll
    for (int h = 0; h < 4; ++h) {
        qp[h] += __shfl_xor(qp[h], 16); qp[h] += __shfl_xor(qp[h], 32);
        kp[h] += __shfl_xor(kp[h], 16); kp[h] += __shfl_xor(kp[h], 32);
    }

    const int cnt = m0 + m1 + m2;

    float wgt[4];
    #pragma unroll
    for (int h = 0; h < 4; ++h) {
        const float q = qp[h];
        const float qk = q + kp[h];
        const float a = q  > 0.f ? q  : NEG * q;    // inactive-relation logit
        const float b = qk > 0.f ? qk : NEG * qk;   // active/self logit
        const float mx = fmaxf(a, b);
        const float eb = (float)(cnt + 1) * __expf(b - mx);
        const float ea = (float)(3 - cnt) * __expf(a - mx);
        wgt[h] = eb / (eb + ea);
    }

    float sum = 0.f, ssq = 0.f;
    #pragma unroll
    for (int mt = 0; mt < 16; ++mt) {
        const float w = wgt[mt >> 2];
        #pragma unroll
        for (int r = 0; r < 4; ++r) {
            float v = fmaxf(acc[mt][r] * w, 0.f);   // ReLU
            acc[mt][r] = v;
            sum += v; ssq += v * v;
        }
    }
    sum += __shfl_xor(sum, 16); sum += __shfl_xor(sum, 32);
    ssq += __shfl_xor(ssq, 16); ssq += __shfl_xor(ssq, 32);
    const float mu = sum * (1.f / 256.f);
    const float var = ssq * (1.f / 256.f) - mu * mu;
    const float rstd = rsqrtf(var + LN_EPS);

    if (valid) {
        float* optr = out + (size_t)node * DIM;
        #pragma unroll
        for (int mt = 0; mt < 16; ++mt) {
            const int cbase = mt * 16 + quad * 4;
            const float4 g = *(const float4*)(gamma + cbase);
            const float4 b = *(const float4*)(beta_p + cbase);
            float4 r;
            r.x = (acc[mt][0] - mu) * rstd * g.x + b.x;
            r.y = (acc[mt][1] - mu) * rstd * g.y + b.y;
            r.z = (acc[mt][2] - mu) * rstd * g.z + b.z;
            r.w = (acc[mt][3] - mu) * rstd * g.w + b.w;
            *(float4*)(optr + cbase) = r;
        }
    }
}

extern "C" void kernel_launch(void* const* d_in, const int* in_sizes, int n_in,
                              void* d_out, int out_size, void* d_ws, size_t ws_size,
                              hipStream_t stream) {
    const float* feat  = (const float*)d_in[0];
    // d_in[1] Wl, d_in[2] bl, d_in[5] attn_l, d_in[6] attn_r, edge_src_*: dead code
    const float* Wr    = (const float*)d_in[3];
    const float* br    = (const float*)d_in[4];
    const float* rel_q = (const float*)d_in[7];
    const float* rel_k = (const float*)d_in[8];
    const float* gamma = (const float*)d_in[9];
    const float* beta  = (const float*)d_in[10];
    const int* dst0 = (const int*)d_in[12];
    const int* dst1 = (const int*)d_in[14];
    const int* dst2 = (const int*)d_in[16];
    const int E = in_sizes[12];

    // d_ws layout: WrF fragment-ordered bf16 (131072 B) | byte mask (150016 B)
    unsigned short* WrF = (unsigned short*)d_ws;
    unsigned char* mask = (unsigned char*)d_ws + DIM * DIM * 2;

    hipMemsetAsync(mask, 0, 150016, stream);
    prep<<<32 + SCAT_BLOCKS, 256, 0, stream>>>(Wr, WrF, dst0, dst1, dst2, E, mask);
    fused_mfma<<<(N_NODES + 63) / 64, 256, 0, stream>>>(
        feat, WrF, br, rel_q, rel_k, gamma, beta, mask, (float*)d_out);
}

// Round 9
// 156.107 us; speedup vs baseline: 2.8186x; 1.0211x over previous
//
#include <hip/hip_runtime.h>

#define N_NODES 50000
#define DIM 256
#define NEG 0.2f
#define LN_EPS 1e-5f
#define SCAT_BLOCKS 2048

typedef __attribute__((ext_vector_type(8))) short short8;   // 8 x bf16 (4 VGPRs)
typedef __attribute__((ext_vector_type(4))) float f32x4;    // MFMA accumulator

__device__ __forceinline__ unsigned short f2bf(float x) {   // RNE fp32 -> bf16
    unsigned int u = __builtin_bit_cast(unsigned int, x);
    u += 0x7fffu + ((u >> 16) & 1u);
    return (unsigned short)(u >> 16);
}

__device__ __forceinline__ void load_lds16(const void* g, void* l) {
    // async global->LDS, 16B/lane, dest = wave-uniform base + lane*16 (linear)
    __builtin_amdgcn_global_load_lds((const unsigned int*)g, (unsigned int*)l, 16, 0, 0);
}

__device__ __forceinline__ short8 cvt_bfrag(float4 a4, float4 b4) {
    short8 r;
    r[0] = (short)f2bf(a4.x); r[1] = (short)f2bf(a4.y);
    r[2] = (short)f2bf(a4.z); r[3] = (short)f2bf(a4.w);
    r[4] = (short)f2bf(b4.x); r[5] = (short)f2bf(b4.y);
    r[6] = (short)f2bf(b4.z); r[7] = (short)f2bf(b4.w);
    return r;
}

// ---------- prep: Wr -> fragment-ordered bf16 WrF  +  relation byte-mask scatter ----------
// WrF layout (proven r2-r8): frag f = kk*16+mt (kk = 32-wide k-step, mt = 16-col m-tile),
// 64 lanes x 16B: WrF[(f*64+lane)*8 + j] = bf16(Wr[kk*32 + (lane>>4)*8 + j][mt*16 + (lane&15)])
__global__ __launch_bounds__(256) void prep(
    const float* __restrict__ Wr, unsigned short* __restrict__ WrF,
    const int* __restrict__ d0, const int* __restrict__ d1, const int* __restrict__ d2,
    int E, unsigned char* __restrict__ mask)
{
    if (blockIdx.x < 32) {                       // 32*256 = 8192 = 128 frags x 64 lanes
        const int o    = blockIdx.x * 256 + threadIdx.x;
        const int lane = o & 63;
        const int frag = o >> 6;                 // kk*16 + mt
        const int mt = frag & 15, kk = frag >> 4;
        const int ln = lane & 15, quad = lane >> 4;
        const float* src = Wr + (size_t)(kk * 32 + quad * 8) * DIM + mt * 16 + ln;
        short8 v;
        #pragma unroll
        for (int j = 0; j < 8; ++j) v[j] = (short)f2bf(src[(size_t)j * DIM]);
        *(short8*)(WrF + (size_t)o * 8) = v;
    } else {
        // racing byte-stores of the same value are benign; memset zeroed the mask
        const int total = 3 * E;
        for (int i = (blockIdx.x - 32) * 256 + (int)threadIdx.x; i < total;
             i += SCAT_BLOCKS * 256) {
            const int* d; int base, e;
            if (i >= 2 * E)  { d = d2; e = i - 2 * E; base = 2 * N_NODES; }
            else if (i >= E) { d = d1; e = i - E;     base = N_NODES; }
            else             { d = d0; e = i;         base = 0; }
            mask[base + d[e]] = (unsigned char)1;
        }
    }
}

// ---------- fused MFMA GEMM + analytic-collapse epilogue (r8 base + coalesced C-store) ----------
// Block = 4 waves x 16 nodes, 2 blocks/CU (2 x 80 KB LDS). r8-proven schedule:
//   stage ksteps 0-4 (80 KB) + feat prefetch + bfr convert -> sync -> MFMA k0-3
//   -> sync -> restage k5-7 || MFMA k4 (resident B region) -> sync -> MFMA k5-7.
// NEW: the node-major C-store (16 cache lines PER instruction, 16B/line -> L2
// transaction-rate bound at ~1.6 TB/s, the measured hbm_gbps ceiling) is replaced
// by an LDS transpose: after the last MFMA all 80 KB LDS are dead; each wave
// writes acc into a private 16 KB slice (XOR-swizzle (ln&7)<<4: <=2-way banks),
// waits lgkmcnt, reads rows dense (matched swizzle) and stores 1 KB/instruction
// fully coalesced. Values bit-identical; only the register->HBM path changes.
__global__ __launch_bounds__(256, 2) void fused_mfma(
    const float* __restrict__ feat, const unsigned short* __restrict__ WrF,
    const float* __restrict__ br, const float* __restrict__ rel_q,
    const float* __restrict__ rel_k, const float* __restrict__ gamma,
    const float* __restrict__ beta_p, const unsigned char* __restrict__ mask,
    float* __restrict__ out)
{
    __shared__ unsigned short lds[40960];        // 80 KB: A=[0,64K) ping, B=[64K,80K) kstep4
    const int lane = threadIdx.x & 63;
    const int wave = threadIdx.x >> 6;
    const int ln = lane & 15;      // node within wave / MFMA n
    const int quad = lane >> 4;    // MFMA k-quad & D-row-quad
    int node = blockIdx.x * 64 + wave * 16 + ln;
    const bool valid = node < N_NODES;
    if (!valid) node = N_NODES - 1;              // clamp: loads safe, store guarded

    // ---- stage ksteps 0-3 into A (16 x 1KB per wave) + kstep 4 into B (4 x 1KB) ----
    {
        const char* g = (const char*)WrF;
        #pragma unroll
        for (int r = 0; r < 16; ++r) {
            const int off = wave * 16384 + r * 1024;     // wave-uniform LDS base
            load_lds16(g + off + lane * 16, (char*)lds + off);
        }
        #pragma unroll
        for (int r = 0; r < 4; ++r) {
            const int off = wave * 4096 + r * 1024;      // within kstep-4 block
            load_lds16(g + 65536 + off + lane * 16, (char*)lds + 65536 + off);
        }
    }

    // mask bytes (epilogue-only; hide latency now)
    const int m0 = (int)mask[node];
    const int m1 = (int)mask[N_NODES + node];
    const int m2 = (int)mask[2 * N_NODES + node];

    // full feat-row prefetch + one-time bf16 conversion (r1-proven)
    const float* fptr = feat + (size_t)node * DIM + quad * 8;
    float4 F0[8], F1[8];
    #pragma unroll
    for (int kk = 0; kk < 8; ++kk) {
        F0[kk] = *(const float4*)(fptr + kk * 32);
        F1[kk] = *(const float4*)(fptr + kk * 32 + 4);
    }
    short8 bfr[8];
    #pragma unroll
    for (int kk = 0; kk < 8; ++kk) bfr[kk] = cvt_bfrag(F0[kk], F1[kk]);

    f32x4 acc[16];
    #pragma unroll
    for (int mt = 0; mt < 16; ++mt) acc[mt] = (f32x4){0.f, 0.f, 0.f, 0.f};

    __syncthreads();                             // vmcnt drain: ksteps 0-4 staged

    #pragma unroll
    for (int kk = 0; kk < 4; ++kk) {
        #pragma unroll
        for (int mt = 0; mt < 16; ++mt) {
            const short8 a = *(const short8*)((const char*)lds
                               + (kk * 16 + mt) * 1024 + lane * 16);
            acc[mt] = __builtin_amdgcn_mfma_f32_16x16x32_bf16(a, bfr[kk], acc[mt], 0, 0, 0);
        }
    }

    __syncthreads();                             // all waves done reading A (ksteps 0-3)

    // issue restage of ksteps 5-7 into A (48 chunks: 12 x 1KB per wave) ...
    {
        const char* g = (const char*)WrF + 81920;        // kstep-5 source base
        #pragma unroll
        for (int r = 0; r < 12; ++r) {
            const int off = (wave * 12 + r) * 1024;
            load_lds16(g + off + lane * 16, (char*)lds + off);
        }
    }
    // ... and compute kstep 4 from resident B while those loads are in flight
    #pragma unroll
    for (int mt = 0; mt < 16; ++mt) {
        const short8 a = *(const short8*)((const char*)lds
                           + 65536 + mt * 1024 + lane * 16);
        acc[mt] = __builtin_amdgcn_mfma_f32_16x16x32_bf16(a, bfr[4], acc[mt], 0, 0, 0);
    }

    __syncthreads();                             // vmcnt drain: ksteps 5-7 staged

    #pragma unroll
    for (int kk = 5; kk < 8; ++kk) {
        #pragma unroll
        for (int mt = 0; mt < 16; ++mt) {
            const short8 a = *(const short8*)((const char*)lds
                               + ((kk - 5) * 16 + mt) * 1024 + lane * 16);
            acc[mt] = __builtin_amdgcn_mfma_f32_16x16x32_bf16(a, bfr[kk], acc[mt], 0, 0, 0);
        }
    }

    // ---- epilogue: bias, per-head dots, softmax weight, ReLU, LayerNorm (verbatim r8) ----
    float qp[4] = {0.f, 0.f, 0.f, 0.f}, kp[4] = {0.f, 0.f, 0.f, 0.f};
    #pragma unroll
    for (int mt = 0; mt < 16; ++mt) {
        const int cbase = mt * 16 + quad * 4;
        const float4 bb = *(const float4*)(br + cbase);
        acc[mt][0] += bb.x; acc[mt][1] += bb.y; acc[mt][2] += bb.z; acc[mt][3] += bb.w;
        const float4 rq = *(const float4*)(rel_q + cbase);
        const float4 rk = *(const float4*)(rel_k + cbase);
        const int h = mt >> 2;
        qp[h] += acc[mt][0] * rq.x + acc[mt][1] * rq.y + acc[mt][2] * rq.z + acc[mt][3] * rq.w;
        kp[h] += acc[mt][0] * rk.x + acc[mt][1] * rk.y + acc[mt][2] * rk.z + acc[mt][3] * rk.w;
    }
    #pragma unroll
    for (int h = 0; h < 4; ++h) {
        qp[h] += __shfl_xor(qp[h], 16); qp[h] += __shfl_xor(qp[h], 32);
        kp[h] += __shfl_xor(kp[h], 16); kp[h] += __shfl_xor(kp[h], 32);
    }

    const int cnt = m0 + m1 + m2;

    float wgt[4];
    #pragma unroll
    for (int h = 0; h < 4; ++h) {
        const float q = qp[h];
        const float qk = q + kp[h];
        const float a = q  > 0.f ? q  : NEG * q;    // inactive-relation logit
        const float b = qk > 0.f ? qk : NEG * qk;   // active/self logit
        const float mx = fmaxf(a, b);
        const float eb = (float)(cnt + 1) * __expf(b - mx);
        const float ea = (float)(3 - cnt) * __expf(a - mx);
        wgt[h] = eb / (eb + ea);
    }

    float sum = 0.f, ssq = 0.f;
    #pragma unroll
    for (int mt = 0; mt < 16; ++mt) {
        const float w = wgt[mt >> 2];
        #pragma unroll
        for (int r = 0; r < 4; ++r) {
            float v = fmaxf(acc[mt][r] * w, 0.f);   // ReLU
            acc[mt][r] = v;
            sum += v; ssq += v * v;
        }
    }
    sum += __shfl_xor(sum, 16); sum += __shfl_xor(sum, 32);
    ssq += __shfl_xor(ssq, 16); ssq += __shfl_xor(ssq, 32);
    const float mu = sum * (1.f / 256.f);
    const float var = ssq * (1.f / 256.f) - mu * mu;
    const float rstd = rsqrtf(var + LN_EPS);

    #pragma unroll
    for (int mt = 0; mt < 16; ++mt) {
        const int cbase = mt * 16 + quad * 4;
        const float4 g = *(const float4*)(gamma + cbase);
        const float4 b = *(const float4*)(beta_p + cbase);
        acc[mt][0] = (acc[mt][0] - mu) * rstd * g.x + b.x;
        acc[mt][1] = (acc[mt][1] - mu) * rstd * g.y + b.y;
        acc[mt][2] = (acc[mt][2] - mu) * rstd * g.z + b.z;
        acc[mt][3] = (acc[mt][3] - mu) * rstd * g.w + b.w;
    }

    // ---- coalesced C-store via LDS transpose (wave-private 16 KB slice) ----
    __syncthreads();                             // all waves done reading W; LDS reusable
    {
        char* slice = (char*)lds + wave * 16384;
        #pragma unroll
        for (int mt = 0; mt < 16; ++mt) {        // node-major write, XOR-swizzled cols
            const int col = (mt * 64 + quad * 16) ^ ((ln & 7) << 4);
            *(f32x4*)(slice + ln * 1024 + col) = acc[mt];
        }
        asm volatile("s_waitcnt lgkmcnt(0)" ::: "memory");
        __builtin_amdgcn_sched_barrier(0);
        const int base_node = blockIdx.x * 64 + wave * 16;
        #pragma unroll
        for (int r = 0; r < 16; ++r) {           // dense row reads + coalesced stores
            if (base_node + r < N_NODES) {       // wave-uniform guard
                const int off = (lane * 16) ^ ((r & 7) << 4);
                const float4 v = *(const float4*)(slice + r * 1024 + off);
                *(float4*)(out + (size_t)(base_node + r) * DIM + lane * 4) = v;
            }
        }
    }
}

extern "C" void kernel_launch(void* const* d_in, const int* in_sizes, int n_in,
                              void* d_out, int out_size, void* d_ws, size_t ws_size,
                              hipStream_t stream) {
    const float* feat  = (const float*)d_in[0];
    // d_in[1] Wl, d_in[2] bl, d_in[5] attn_l, d_in[6] attn_r, edge_src_*: dead code
    const float* Wr    = (const float*)d_in[3];
    const float* br    = (const float*)d_in[4];
    const float* rel_q = (const float*)d_in[7];
    const float* rel_k = (const float*)d_in[8];
    const float* gamma = (const float*)d_in[9];
    const float* beta  = (const float*)d_in[10];
    const int* dst0 = (const int*)d_in[12];
    const int* dst1 = (const int*)d_in[14];
    const int* dst2 = (const int*)d_in[16];
    const int E = in_sizes[12];

    // d_ws layout: WrF fragment-ordered bf16 (131072 B) | byte mask (150016 B)
    unsigned short* WrF = (unsigned short*)d_ws;
    unsigned char* mask = (unsigned char*)d_ws + DIM * DIM * 2;

    hipMemsetAsync(mask, 0, 150016, stream);
    prep<<<32 + SCAT_BLOCKS, 256, 0, stream>>>(Wr, WrF, dst0, dst1, dst2, E, mask);
    fused_mfma<<<(N_NODES + 63) / 64, 256, 0, stream>>>(
        feat, WrF, br, rel_q, rel_k, gamma, beta, mask, (float*)d_out);
}